// Round 5
// baseline (644.120 us; speedup 1.0000x reference)
//
#include <hip/hip_runtime.h>
#include <hip/hip_bf16.h>
#include <math.h>

#define IN   128
#define HID  64
#define HEADS 4
#define NCLS 10
#define BSH  6                  // bucket shift: 64 dst per bucket
#define SRCMASK 0x03FFFFFF      // low 26 bits = src (n < 67M)

__device__ __forceinline__ float lrelu02(float x) { return fmaxf(x, 0.2f * x); }

template<int CTRL>
__device__ __forceinline__ float dppadd(float x) {
    int y = __builtin_amdgcn_update_dpp(0, __float_as_int(x), CTRL, 0xF, 0xF, true);
    return x + __int_as_float(y);
}
// sum over each 16-lane group (head): pure-VALU DPP tree
__device__ __forceinline__ float sum16(float p) {
    p = dppadd<0x128>(p);  // row_ror:8
    p = dppadd<0x124>(p);  // row_ror:4
    p = dppadd<0x4E>(p);   // quad_perm xor2
    p = dppadd<0xB1>(p);   // quad_perm xor1
    return p;
}

// ---------------- K1: h0 = x @ W_pre  (blocks < rb)  +  dst histogram (blocks >= rb) ----------------
__global__ __launch_bounds__(256) void k_pre_hist(const float* __restrict__ x,
                                                  const float* __restrict__ Wp,
                                                  float* __restrict__ h0, int n,
                                                  const int* __restrict__ dst, int* __restrict__ cnt,
                                                  int E, int rb)
{
    __shared__ float sW[IN * HID];
    __shared__ float sx[64][IN + 4];
    int t = threadIdx.x;
    if ((int)blockIdx.x >= rb) {
        int e = ((int)blockIdx.x - rb) * 256 + t;
        if (e < E) atomicAdd(&cnt[dst[e]], 1);
        return;
    }
    for (int i = 4 * t; i < IN * HID; i += 1024)
        *(float4*)&sW[i] = *(const float4*)&Wp[i];
    int row0 = blockIdx.x * 64;
    for (int i = t; i < 64 * (IN / 4); i += 256) {
        int r = i >> 5;
        int c4 = (i & 31) * 4;
        int row = row0 + r;
        float4 v = make_float4(0.f, 0.f, 0.f, 0.f);
        if (row < n) v = *(const float4*)&x[(size_t)row * IN + c4];
        *(float4*)&sx[r][c4] = v;
    }
    __syncthreads();
    int tc = t & 15, tr = t >> 4;
    int c0 = tc * 4, r0 = tr * 4;
    float acc[4][4] = {};
    #pragma unroll 4
    for (int k = 0; k < IN; k++) {
        float4 w = *(float4*)&sW[k * HID + c0];
        #pragma unroll
        for (int j = 0; j < 4; j++) {
            float xv = sx[r0 + j][k];
            acc[j][0] += xv * w.x; acc[j][1] += xv * w.y;
            acc[j][2] += xv * w.z; acc[j][3] += xv * w.w;
        }
    }
    #pragma unroll
    for (int j = 0; j < 4; j++) {
        int row = row0 + r0 + j;
        if (row < n)
            *(float4*)&h0[(size_t)row * HID + c0] =
                make_float4(acc[j][0], acc[j][1], acc[j][2], acc[j][3]);
    }
}

// ---------------- K2: xl/xr projections (blocks < rb) + scan stage1 (blocks >= rb) ----------------
__global__ __launch_bounds__(256) void k_lr_scan1(const float* __restrict__ h0,
                                                  const float* __restrict__ Wl, const float* __restrict__ bl,
                                                  const float* __restrict__ Wr, const float* __restrict__ br,
                                                  float* __restrict__ xl, float* __restrict__ xr, int n,
                                                  const int* __restrict__ cnt, int* __restrict__ off,
                                                  int* __restrict__ bsum, int rb)
{
    __shared__ float smem[12672];
    int t = threadIdx.x;

    if ((int)blockIdx.x >= rb) {
        int* si = (int*)smem;
        int bid = (int)blockIdx.x - rb;
        int base = bid * 1024 + t * 4;
        int c0 = 0, c1 = 0, c2 = 0, c3 = 0;
        if (base + 3 < n) {
            int4 c = *(const int4*)&cnt[base];
            c0 = c.x; c1 = c.y; c2 = c.z; c3 = c.w;
        } else {
            if (base     < n) c0 = cnt[base];
            if (base + 1 < n) c1 = cnt[base + 1];
            if (base + 2 < n) c2 = cnt[base + 2];
            if (base + 3 < n) c3 = cnt[base + 3];
        }
        int lsum = c0 + c1 + c2 + c3;
        si[t] = lsum;
        __syncthreads();
        for (int d = 1; d < 256; d <<= 1) {
            int add = (t >= d) ? si[t - d] : 0;
            __syncthreads();
            si[t] += add;
            __syncthreads();
        }
        int excl = si[t] - lsum;
        if (base     < n) off[base]     = excl;
        if (base + 1 < n) off[base + 1] = excl + c0;
        if (base + 2 < n) off[base + 2] = excl + c0 + c1;
        if (base + 3 < n) off[base + 3] = excl + c0 + c1 + c2;
        if (t == 255) bsum[bid] = si[255];
        return;
    }

    float* sWl = smem;
    float* sWr = smem + 4096;
    float* sh  = smem + 8192;
    float* sbl = smem + 12544;
    float* sbr = smem + 12608;
    for (int i = 4 * t; i < HID * HID; i += 1024) {
        *(float4*)&sWl[i] = *(const float4*)&Wl[i];
        *(float4*)&sWr[i] = *(const float4*)&Wr[i];
    }
    if (t < HID) { sbl[t] = bl[t]; sbr[t] = br[t]; }
    int row0 = blockIdx.x * 64;
    for (int i = t; i < 64 * (HID / 4); i += 256) {
        int r = i >> 4, c4 = (i & 15) * 4;
        int row = row0 + r;
        float4 v = make_float4(0.f, 0.f, 0.f, 0.f);
        if (row < n) v = *(const float4*)&h0[(size_t)row * HID + c4];
        *(float4*)&sh[r * 68 + c4] = v;
    }
    __syncthreads();
    int tc = t & 15, tr = t >> 4;
    int c0 = tc * 4, r0 = tr * 4;
    float accl[4][4] = {}, accr[4][4] = {};
    #pragma unroll 4
    for (int k = 0; k < HID; k++) {
        float4 wl = *(float4*)&sWl[k * HID + c0];
        float4 wr = *(float4*)&sWr[k * HID + c0];
        #pragma unroll
        for (int j = 0; j < 4; j++) {
            float hv = sh[(r0 + j) * 68 + k];
            accl[j][0] += hv * wl.x; accl[j][1] += hv * wl.y;
            accl[j][2] += hv * wl.z; accl[j][3] += hv * wl.w;
            accr[j][0] += hv * wr.x; accr[j][1] += hv * wr.y;
            accr[j][2] += hv * wr.z; accr[j][3] += hv * wr.w;
        }
    }
    float4 b4l = *(float4*)&sbl[c0];
    float4 b4r = *(float4*)&sbr[c0];
    #pragma unroll
    for (int j = 0; j < 4; j++) {
        int row = row0 + r0 + j;
        if (row < n) {
            *(float4*)&xl[(size_t)row * HID + c0] = make_float4(
                accl[j][0] + b4l.x, accl[j][1] + b4l.y, accl[j][2] + b4l.z, accl[j][3] + b4l.w);
            *(float4*)&xr[(size_t)row * HID + c0] = make_float4(
                accr[j][0] + b4r.x, accr[j][1] + b4r.y, accr[j][2] + b4r.z, accr[j][3] + b4r.w);
        }
    }
}

// ---------------- Scan stage 2 ----------------
__global__ __launch_bounds__(1024) void k_scan2(const int* __restrict__ bsum, int* __restrict__ boff, int nb)
{
    __shared__ int s[1024];
    int i = threadIdx.x;
    int v = (i < nb) ? bsum[i] : 0;
    s[i] = v;
    __syncthreads();
    for (int d = 1; d < 1024; d <<= 1) {
        int add = (i >= d) ? s[i - d] : 0;
        __syncthreads();
        s[i] += add;
        __syncthreads();
    }
    if (i < nb) boff[i] = s[i] - v;
}

// ---------------- Scan stage 3: finalize off; init per-bucket cursors ----------------
__global__ __launch_bounds__(256) void k_scan3(int* __restrict__ off, const int* __restrict__ boff,
                                               int* __restrict__ bcur, int n)
{
    int i = blockIdx.x * 256 + threadIdx.x;
    if (i < n) {
        int o = off[i] + boff[i >> 10];
        off[i] = o;
        if ((i & 63) == 0) bcur[i >> BSH] = o;   // bucket start = its final CSR region start
    }
}

// ---------------- Pass A: bucket scatter (append into final region, unsorted within) ----------------
__global__ __launch_bounds__(256) void k_bucket(const int* __restrict__ src, const int* __restrict__ dst,
                                                const float* __restrict__ ew,
                                                int* __restrict__ bcur,
                                                int2* __restrict__ stage, int E)
{
    int e4 = (blockIdx.x * 256 + threadIdx.x) * 4;
    if (e4 + 3 < E) {
        int4   s4 = *(const int4*)&src[e4];
        int4   d4 = *(const int4*)&dst[e4];
        float4 w4 = *(const float4*)&ew[e4];
        int p;
        p = atomicAdd(&bcur[d4.x >> BSH], 1);
        stage[p] = make_int2(s4.x | ((d4.x & 63) << 26), __float_as_int(w4.x));
        p = atomicAdd(&bcur[d4.y >> BSH], 1);
        stage[p] = make_int2(s4.y | ((d4.y & 63) << 26), __float_as_int(w4.y));
        p = atomicAdd(&bcur[d4.z >> BSH], 1);
        stage[p] = make_int2(s4.z | ((d4.z & 63) << 26), __float_as_int(w4.z));
        p = atomicAdd(&bcur[d4.w >> BSH], 1);
        stage[p] = make_int2(s4.w | ((d4.w & 63) << 26), __float_as_int(w4.w));
    } else {
        for (int e = e4; e < E; e++) {
            int d = dst[e];
            int p = atomicAdd(&bcur[d >> BSH], 1);
            stage[p] = make_int2(src[e] | ((d & 63) << 26), __float_as_int(ew[e]));
        }
    }
}

// ---------------- Pass B: sort within bucket via LDS cursors; write clean (src,w) ----------------
__global__ __launch_bounds__(256) void k_sortB(const int* __restrict__ off,
                                               const int2* __restrict__ stage,
                                               int2* __restrict__ csr, int n, int E)
{
    __shared__ int cur[64];
    int b = blockIdx.x;
    int v0 = b << BSH;
    int t = threadIdx.x;
    if (t < 64) cur[t] = (v0 + t < n) ? off[v0 + t] : E;
    int beg = off[v0];
    int vend = v0 + 64;
    int end = (vend < n) ? off[vend] : E;
    __syncthreads();
    for (int i = beg + t; i < end; i += 256) {
        int2 e = stage[i];
        int dl = ((unsigned)e.x) >> 26;
        int p = atomicAdd(&cur[dl], 1);
        csr[p] = make_int2(e.x & SRCMASK, e.y);
    }
}

// ---------------- K_agg: one wave per dst; scalar-addressed gathers; DPP reduction ----------------
__global__ __launch_bounds__(256) void k_agg(const int* __restrict__ off,
                                             const int2* __restrict__ csr,
                                             const float* __restrict__ xl, const float* __restrict__ xr,
                                             const float* __restrict__ h0,
                                             const float* __restrict__ We, const float* __restrict__ att,
                                             const float* __restrict__ gb,
                                             float* __restrict__ hout, int n, int E)
{
    __shared__ float sWe[HID], sAtt[HID], sGb[HID];
    int t = threadIdx.x;
    if (t < HID) { sWe[t] = We[t]; sAtt[t] = att[t]; sGb[t] = gb[t]; }
    __syncthreads();
    int lane = t & 63;
    int v = blockIdx.x * 4 + (t >> 6);
    if (v >= n) return;

    int beg = off[v];
    int end = (v == n - 1) ? E : off[v + 1];

    float we = sWe[lane], at = sAtt[lane];
    float xrv = xr[(size_t)v * HID + lane];
    float xlv = xl[(size_t)v * HID + lane];

    float num = 0.f, den = 0.f, wsum = 0.f;

    for (int base = beg; base < end; base += 64) {
        int m = end - base; if (m > 64) m = 64;
        int sv = 0, wvb = 0;
        if (lane < m) {
            int2 cw = csr[base + lane];
            sv = cw.x;
            wvb = cw.y;
        }
        for (int j0 = 0; j0 < m; j0 += 4) {
            float xls[4], wj[4];
            #pragma unroll
            for (int u = 0; u < 4; u++) {
                if (j0 + u < m) {
                    int ss = __builtin_amdgcn_readlane(sv, j0 + u);
                    int wb = __builtin_amdgcn_readlane(wvb, j0 + u);
                    wj[u] = __int_as_float(wb);
                    const float* ps = xl + ((unsigned)ss << 6);
                    xls[u] = ps[lane];
                }
            }
            #pragma unroll
            for (int u = 0; u < 4; u++) {
                if (j0 + u < m) {
                    float ef = lrelu02(xls[u] + xrv + wj[u] * we);
                    float p = sum16(ef * at);
                    float ex = __expf(p);
                    num += ex * xls[u];
                    den += ex;
                    wsum += wj[u];
                }
            }
        }
    }

    float cntf = (float)(end - beg);
    float la = wsum / fmaxf(cntf, 1.0f);
    float ef = lrelu02(xlv + xrv + la * we);
    float p = sum16(ef * at);
    float exs = __expf(p);
    den += exs;
    num += exs * xlv;

    float o = num / den + sGb[lane];
    float h1 = o > 0.f ? o : expm1f(o);
    hout[(size_t)v * HID + lane] = h0[(size_t)v * HID + lane] + h1;
}

// ---------------- K_mlp: logits = relu(h@W1+b1)@W2+b2 ----------------
__global__ __launch_bounds__(256) void k_mlp(const float* __restrict__ h,
                                             const float* __restrict__ W1, const float* __restrict__ b1,
                                             const float* __restrict__ W2, const float* __restrict__ b2,
                                             float* __restrict__ logits, int n)
{
    __shared__ float sW1[HID * HID];
    __shared__ float sh[64][HID + 4];
    __shared__ float sz[64][HID + 4];
    __shared__ float sW2[HID * NCLS];
    __shared__ float sb1[HID], sb2[NCLS];
    int t = threadIdx.x;
    for (int i = 4 * t; i < HID * HID; i += 1024)
        *(float4*)&sW1[i] = *(const float4*)&W1[i];
    if (4 * t < HID * NCLS)
        *(float4*)&sW2[4 * t] = *(const float4*)&W2[4 * t];
    if (t < HID)  sb1[t] = b1[t];
    if (t < NCLS) sb2[t] = b2[t];
    int row0 = blockIdx.x * 64;
    for (int i = t; i < 64 * (HID / 4); i += 256) {
        int r = i >> 4, c4 = (i & 15) * 4;
        int row = row0 + r;
        float4 v = make_float4(0.f, 0.f, 0.f, 0.f);
        if (row < n) v = *(const float4*)&h[(size_t)row * HID + c4];
        *(float4*)&sh[r][c4] = v;
    }
    __syncthreads();
    int tc = t & 15, tr = t >> 4;
    int c0 = tc * 4, r0 = tr * 4;
    float4 b14 = *(float4*)&sb1[c0];
    float acc[4][4];
    #pragma unroll
    for (int j = 0; j < 4; j++) { acc[j][0] = b14.x; acc[j][1] = b14.y; acc[j][2] = b14.z; acc[j][3] = b14.w; }
    #pragma unroll 4
    for (int k = 0; k < HID; k++) {
        float4 w = *(float4*)&sW1[k * HID + c0];
        #pragma unroll
        for (int j = 0; j < 4; j++) {
            float hv = sh[r0 + j][k];
            acc[j][0] += hv * w.x; acc[j][1] += hv * w.y;
            acc[j][2] += hv * w.z; acc[j][3] += hv * w.w;
        }
    }
    #pragma unroll
    for (int j = 0; j < 4; j++) {
        sz[r0 + j][c0 + 0] = fmaxf(acc[j][0], 0.f);
        sz[r0 + j][c0 + 1] = fmaxf(acc[j][1], 0.f);
        sz[r0 + j][c0 + 2] = fmaxf(acc[j][2], 0.f);
        sz[r0 + j][c0 + 3] = fmaxf(acc[j][3], 0.f);
    }
    __syncthreads();
    for (int i = t; i < 64 * NCLS; i += 256) {
        int r = i / NCLS, c = i - r * NCLS;
        int row = row0 + r;
        float s = sb2[c];
        #pragma unroll 8
        for (int k = 0; k < HID; k++) s += sz[r][k] * sW2[k * NCLS + c];
        if (row < n) logits[(size_t)row * NCLS + c] = s;
    }
}

extern "C" void kernel_launch(void* const* d_in, const int* in_sizes, int n_in,
                              void* d_out, int out_size, void* d_ws, size_t ws_size,
                              hipStream_t stream)
{
    const float* x   = (const float*)d_in[0];
    const float* ew  = (const float*)d_in[1];
    const float* Wp  = (const float*)d_in[2];
    const float* Wl  = (const float*)d_in[3];
    const float* bl  = (const float*)d_in[4];
    const float* Wr  = (const float*)d_in[5];
    const float* br  = (const float*)d_in[6];
    const float* att = (const float*)d_in[7];
    const float* We  = (const float*)d_in[8];
    const float* gb  = (const float*)d_in[9];
    const float* W1  = (const float*)d_in[10];
    const float* b1  = (const float*)d_in[11];
    const float* W2  = (const float*)d_in[12];
    const float* b2  = (const float*)d_in[13];
    const int*   ei  = (const int*)d_in[14];

    int n = in_sizes[0] / IN;
    int E = in_sizes[1];
    const int* src = ei;
    const int* dst = ei + E;

    int nbk = (n + 63) >> BSH;                  // buckets

    float* h0    = (float*)d_ws;
    float* xl    = h0 + (size_t)n * HID;
    float* xr    = xl + (size_t)n * HID;
    int*   cnt   = (int*)(xr + (size_t)n * HID);   // zeroed
    int*   off   = cnt + n;
    int*   bsum  = off + n;
    int*   boff  = bsum + 1024;
    int*   bcur  = boff + 1024;
    int2*  stage = (int2*)(bcur + ((nbk + 1) & ~1));
    int2*  csr   = stage + E;

    float* hout   = (float*)d_out;
    float* logits = hout + (size_t)n * HID;

    hipMemsetAsync(cnt, 0, (size_t)n * sizeof(int), stream);

    int rb = (n + 63) / 64;
    int nb = (n + 1023) / 1024;
    int Eb = (E + 255) / 256;

    k_pre_hist<<<rb + Eb, 256, 0, stream>>>(x, Wp, h0, n, dst, cnt, E, rb);
    k_lr_scan1<<<rb + nb, 256, 0, stream>>>(h0, Wl, bl, Wr, br, xl, xr, n, cnt, off, bsum, rb);
    k_scan2<<<1, 1024, 0, stream>>>(bsum, boff, nb);
    k_scan3<<<(n + 255) / 256, 256, 0, stream>>>(off, boff, bcur, n);
    k_bucket<<<(E / 4 + 255) / 256, 256, 0, stream>>>(src, dst, ew, bcur, stage, E);
    k_sortB<<<nbk, 256, 0, stream>>>(off, stage, csr, n, E);
    k_agg <<<(n + 3) / 4, 256, 0, stream>>>(off, csr, xl, xr, h0, We, att, gb, hout, n, E);
    k_mlp <<<rb, 256, 0, stream>>>(hout, W1, b1, W2, b2, logits, n);
}

// Round 6
// 428.984 us; speedup vs baseline: 1.5015x; 1.5015x over previous
//
#include <hip/hip_runtime.h>
#include <hip/hip_bf16.h>
#include <math.h>

#define IN   128
#define HID  64
#define HEADS 4
#define NCLS 10

__device__ __forceinline__ float lrelu02(float x) { return fmaxf(x, 0.2f * x); }

template<int CTRL>
__device__ __forceinline__ float dppadd(float x) {
    int y = __builtin_amdgcn_update_dpp(0, __float_as_int(x), CTRL, 0xF, 0xF, true);
    return x + __int_as_float(y);
}
// sum over each 16-lane group (head): pure-VALU DPP tree
__device__ __forceinline__ float sum16(float p) {
    p = dppadd<0x128>(p);  // row_ror:8
    p = dppadd<0x124>(p);  // row_ror:4
    p = dppadd<0x4E>(p);   // quad_perm xor2
    p = dppadd<0xB1>(p);   // quad_perm xor1
    return p;
}

// ---------------- K1: h0 = x @ W_pre (blocks < rb) + dst histogram w/ rank capture (blocks >= rb) ----------------
__global__ __launch_bounds__(256) void k_pre_hist(const float* __restrict__ x,
                                                  const float* __restrict__ Wp,
                                                  float* __restrict__ h0, int n,
                                                  const int* __restrict__ dst, int* __restrict__ cnt,
                                                  int* __restrict__ rank, int E, int rb)
{
    __shared__ float sW[IN * HID];
    __shared__ float sx[64][IN + 4];
    int t = threadIdx.x;
    if ((int)blockIdx.x >= rb) {
        int e = ((int)blockIdx.x - rb) * 256 + t;
        if (e < E) rank[e] = atomicAdd(&cnt[dst[e]], 1);   // rank within dst segment
        return;
    }
    for (int i = 4 * t; i < IN * HID; i += 1024)
        *(float4*)&sW[i] = *(const float4*)&Wp[i];
    int row0 = blockIdx.x * 64;
    for (int i = t; i < 64 * (IN / 4); i += 256) {
        int r = i >> 5;
        int c4 = (i & 31) * 4;
        int row = row0 + r;
        float4 v = make_float4(0.f, 0.f, 0.f, 0.f);
        if (row < n) v = *(const float4*)&x[(size_t)row * IN + c4];
        *(float4*)&sx[r][c4] = v;
    }
    __syncthreads();
    int tc = t & 15, tr = t >> 4;
    int c0 = tc * 4, r0 = tr * 4;
    float acc[4][4] = {};
    #pragma unroll 4
    for (int k = 0; k < IN; k++) {
        float4 w = *(float4*)&sW[k * HID + c0];
        #pragma unroll
        for (int j = 0; j < 4; j++) {
            float xv = sx[r0 + j][k];
            acc[j][0] += xv * w.x; acc[j][1] += xv * w.y;
            acc[j][2] += xv * w.z; acc[j][3] += xv * w.w;
        }
    }
    #pragma unroll
    for (int j = 0; j < 4; j++) {
        int row = row0 + r0 + j;
        if (row < n)
            *(float4*)&h0[(size_t)row * HID + c0] =
                make_float4(acc[j][0], acc[j][1], acc[j][2], acc[j][3]);
    }
}

// ---------------- K2: xl/xr projections (blocks < rb) + scan stage1 (blocks >= rb) ----------------
__global__ __launch_bounds__(256) void k_lr_scan1(const float* __restrict__ h0,
                                                  const float* __restrict__ Wl, const float* __restrict__ bl,
                                                  const float* __restrict__ Wr, const float* __restrict__ br,
                                                  float* __restrict__ xl, float* __restrict__ xr, int n,
                                                  const int* __restrict__ cnt, int* __restrict__ off,
                                                  int* __restrict__ bsum, int rb)
{
    __shared__ float smem[12672];
    int t = threadIdx.x;

    if ((int)blockIdx.x >= rb) {
        int* si = (int*)smem;
        int bid = (int)blockIdx.x - rb;
        int base = bid * 1024 + t * 4;
        int c0 = 0, c1 = 0, c2 = 0, c3 = 0;
        if (base + 3 < n) {
            int4 c = *(const int4*)&cnt[base];
            c0 = c.x; c1 = c.y; c2 = c.z; c3 = c.w;
        } else {
            if (base     < n) c0 = cnt[base];
            if (base + 1 < n) c1 = cnt[base + 1];
            if (base + 2 < n) c2 = cnt[base + 2];
            if (base + 3 < n) c3 = cnt[base + 3];
        }
        int lsum = c0 + c1 + c2 + c3;
        si[t] = lsum;
        __syncthreads();
        for (int d = 1; d < 256; d <<= 1) {
            int add = (t >= d) ? si[t - d] : 0;
            __syncthreads();
            si[t] += add;
            __syncthreads();
        }
        int excl = si[t] - lsum;
        if (base     < n) off[base]     = excl;
        if (base + 1 < n) off[base + 1] = excl + c0;
        if (base + 2 < n) off[base + 2] = excl + c0 + c1;
        if (base + 3 < n) off[base + 3] = excl + c0 + c1 + c2;
        if (t == 255) bsum[bid] = si[255];
        return;
    }

    float* sWl = smem;
    float* sWr = smem + 4096;
    float* sh  = smem + 8192;
    float* sbl = smem + 12544;
    float* sbr = smem + 12608;
    for (int i = 4 * t; i < HID * HID; i += 1024) {
        *(float4*)&sWl[i] = *(const float4*)&Wl[i];
        *(float4*)&sWr[i] = *(const float4*)&Wr[i];
    }
    if (t < HID) { sbl[t] = bl[t]; sbr[t] = br[t]; }
    int row0 = blockIdx.x * 64;
    for (int i = t; i < 64 * (HID / 4); i += 256) {
        int r = i >> 4, c4 = (i & 15) * 4;
        int row = row0 + r;
        float4 v = make_float4(0.f, 0.f, 0.f, 0.f);
        if (row < n) v = *(const float4*)&h0[(size_t)row * HID + c4];
        *(float4*)&sh[r * 68 + c4] = v;
    }
    __syncthreads();
    int tc = t & 15, tr = t >> 4;
    int c0 = tc * 4, r0 = tr * 4;
    float accl[4][4] = {}, accr[4][4] = {};
    #pragma unroll 4
    for (int k = 0; k < HID; k++) {
        float4 wl = *(float4*)&sWl[k * HID + c0];
        float4 wr = *(float4*)&sWr[k * HID + c0];
        #pragma unroll
        for (int j = 0; j < 4; j++) {
            float hv = sh[(r0 + j) * 68 + k];
            accl[j][0] += hv * wl.x; accl[j][1] += hv * wl.y;
            accl[j][2] += hv * wl.z; accl[j][3] += hv * wl.w;
            accr[j][0] += hv * wr.x; accr[j][1] += hv * wr.y;
            accr[j][2] += hv * wr.z; accr[j][3] += hv * wr.w;
        }
    }
    float4 b4l = *(float4*)&sbl[c0];
    float4 b4r = *(float4*)&sbr[c0];
    #pragma unroll
    for (int j = 0; j < 4; j++) {
        int row = row0 + r0 + j;
        if (row < n) {
            *(float4*)&xl[(size_t)row * HID + c0] = make_float4(
                accl[j][0] + b4l.x, accl[j][1] + b4l.y, accl[j][2] + b4l.z, accl[j][3] + b4l.w);
            *(float4*)&xr[(size_t)row * HID + c0] = make_float4(
                accr[j][0] + b4r.x, accr[j][1] + b4r.y, accr[j][2] + b4r.z, accr[j][3] + b4r.w);
        }
    }
}

// ---------------- Scan stage 2 ----------------
__global__ __launch_bounds__(1024) void k_scan2(const int* __restrict__ bsum, int* __restrict__ boff, int nb)
{
    __shared__ int s[1024];
    int i = threadIdx.x;
    int v = (i < nb) ? bsum[i] : 0;
    s[i] = v;
    __syncthreads();
    for (int d = 1; d < 1024; d <<= 1) {
        int add = (i >= d) ? s[i - d] : 0;
        __syncthreads();
        s[i] += add;
        __syncthreads();
    }
    if (i < nb) boff[i] = s[i] - v;
}

// ---------------- Scan stage 3: finalize off ----------------
__global__ __launch_bounds__(256) void k_scan3(int* __restrict__ off, const int* __restrict__ boff, int n)
{
    int i = blockIdx.x * 256 + threadIdx.x;
    if (i < n) off[i] += boff[i >> 10];
}

// ---------------- Scatter into CSR — atomic-free: pos = off[dst] + rank ----------------
__global__ __launch_bounds__(256) void k_scatter(const int* __restrict__ src, const int* __restrict__ dst,
                                                 const float* __restrict__ ew,
                                                 const int* __restrict__ off, const int* __restrict__ rank,
                                                 int2* __restrict__ csr, int E)
{
    int e4 = (blockIdx.x * 256 + threadIdx.x) * 4;
    if (e4 + 3 < E) {
        int4   s4 = *(const int4*)&src[e4];
        int4   d4 = *(const int4*)&dst[e4];
        int4   r4 = *(const int4*)&rank[e4];
        float4 w4 = *(const float4*)&ew[e4];
        // 4 independent L2-hot gathers of off[], then 4 fire-and-forget stores
        int p0 = off[d4.x] + r4.x;
        int p1 = off[d4.y] + r4.y;
        int p2 = off[d4.z] + r4.z;
        int p3 = off[d4.w] + r4.w;
        csr[p0] = make_int2(s4.x, __float_as_int(w4.x));
        csr[p1] = make_int2(s4.y, __float_as_int(w4.y));
        csr[p2] = make_int2(s4.z, __float_as_int(w4.z));
        csr[p3] = make_int2(s4.w, __float_as_int(w4.w));
    } else {
        for (int e = e4; e < E; e++) {
            int p = off[dst[e]] + rank[e];
            csr[p] = make_int2(src[e], __float_as_int(ew[e]));
        }
    }
}

// ---------------- K_agg: one wave per dst; scalar-addressed gathers; DPP reduction ----------------
__global__ __launch_bounds__(256) void k_agg(const int* __restrict__ off,
                                             const int2* __restrict__ csr,
                                             const float* __restrict__ xl, const float* __restrict__ xr,
                                             const float* __restrict__ h0,
                                             const float* __restrict__ We, const float* __restrict__ att,
                                             const float* __restrict__ gb,
                                             float* __restrict__ hout, int n, int E)
{
    __shared__ float sWe[HID], sAtt[HID], sGb[HID];
    int t = threadIdx.x;
    if (t < HID) { sWe[t] = We[t]; sAtt[t] = att[t]; sGb[t] = gb[t]; }
    __syncthreads();
    int lane = t & 63;
    int v = blockIdx.x * 4 + (t >> 6);
    if (v >= n) return;

    int beg = off[v];
    int end = (v == n - 1) ? E : off[v + 1];

    float we = sWe[lane], at = sAtt[lane];
    float xrv = xr[(size_t)v * HID + lane];
    float xlv = xl[(size_t)v * HID + lane];

    float num = 0.f, den = 0.f, wsum = 0.f;

    for (int base = beg; base < end; base += 64) {
        int m = end - base; if (m > 64) m = 64;
        int sv = 0, wvb = 0;
        if (lane < m) {
            int2 cw = csr[base + lane];
            sv = cw.x;
            wvb = cw.y;
        }
        for (int j0 = 0; j0 < m; j0 += 4) {
            float xls[4], wj[4];
            #pragma unroll
            for (int u = 0; u < 4; u++) {
                if (j0 + u < m) {
                    int ss = __builtin_amdgcn_readlane(sv, j0 + u);
                    int wb = __builtin_amdgcn_readlane(wvb, j0 + u);
                    wj[u] = __int_as_float(wb);
                    const float* ps = xl + ((unsigned)ss << 6);
                    xls[u] = ps[lane];
                }
            }
            #pragma unroll
            for (int u = 0; u < 4; u++) {
                if (j0 + u < m) {
                    float ef = lrelu02(xls[u] + xrv + wj[u] * we);
                    float p = sum16(ef * at);
                    float ex = __expf(p);
                    num += ex * xls[u];
                    den += ex;
                    wsum += wj[u];
                }
            }
        }
    }

    float cntf = (float)(end - beg);
    float la = wsum / fmaxf(cntf, 1.0f);
    float ef = lrelu02(xlv + xrv + la * we);
    float p = sum16(ef * at);
    float exs = __expf(p);
    den += exs;
    num += exs * xlv;

    float o = num / den + sGb[lane];
    float h1 = o > 0.f ? o : expm1f(o);
    hout[(size_t)v * HID + lane] = h0[(size_t)v * HID + lane] + h1;
}

// ---------------- K_mlp: logits = relu(h@W1+b1)@W2+b2 ----------------
__global__ __launch_bounds__(256) void k_mlp(const float* __restrict__ h,
                                             const float* __restrict__ W1, const float* __restrict__ b1,
                                             const float* __restrict__ W2, const float* __restrict__ b2,
                                             float* __restrict__ logits, int n)
{
    __shared__ float sW1[HID * HID];
    __shared__ float sh[64][HID + 4];
    __shared__ float sz[64][HID + 4];
    __shared__ float sW2[HID * NCLS];
    __shared__ float sb1[HID], sb2[NCLS];
    int t = threadIdx.x;
    for (int i = 4 * t; i < HID * HID; i += 1024)
        *(float4*)&sW1[i] = *(const float4*)&W1[i];
    if (4 * t < HID * NCLS)
        *(float4*)&sW2[4 * t] = *(const float4*)&W2[4 * t];
    if (t < HID)  sb1[t] = b1[t];
    if (t < NCLS) sb2[t] = b2[t];
    int row0 = blockIdx.x * 64;
    for (int i = t; i < 64 * (HID / 4); i += 256) {
        int r = i >> 4, c4 = (i & 15) * 4;
        int row = row0 + r;
        float4 v = make_float4(0.f, 0.f, 0.f, 0.f);
        if (row < n) v = *(const float4*)&h[(size_t)row * HID + c4];
        *(float4*)&sh[r][c4] = v;
    }
    __syncthreads();
    int tc = t & 15, tr = t >> 4;
    int c0 = tc * 4, r0 = tr * 4;
    float4 b14 = *(float4*)&sb1[c0];
    float acc[4][4];
    #pragma unroll
    for (int j = 0; j < 4; j++) { acc[j][0] = b14.x; acc[j][1] = b14.y; acc[j][2] = b14.z; acc[j][3] = b14.w; }
    #pragma unroll 4
    for (int k = 0; k < HID; k++) {
        float4 w = *(float4*)&sW1[k * HID + c0];
        #pragma unroll
        for (int j = 0; j < 4; j++) {
            float hv = sh[r0 + j][k];
            acc[j][0] += hv * w.x; acc[j][1] += hv * w.y;
            acc[j][2] += hv * w.z; acc[j][3] += hv * w.w;
        }
    }
    #pragma unroll
    for (int j = 0; j < 4; j++) {
        sz[r0 + j][c0 + 0] = fmaxf(acc[j][0], 0.f);
        sz[r0 + j][c0 + 1] = fmaxf(acc[j][1], 0.f);
        sz[r0 + j][c0 + 2] = fmaxf(acc[j][2], 0.f);
        sz[r0 + j][c0 + 3] = fmaxf(acc[j][3], 0.f);
    }
    __syncthreads();
    for (int i = t; i < 64 * NCLS; i += 256) {
        int r = i / NCLS, c = i - r * NCLS;
        int row = row0 + r;
        float s = sb2[c];
        #pragma unroll 8
        for (int k = 0; k < HID; k++) s += sz[r][k] * sW2[k * NCLS + c];
        if (row < n) logits[(size_t)row * NCLS + c] = s;
    }
}

extern "C" void kernel_launch(void* const* d_in, const int* in_sizes, int n_in,
                              void* d_out, int out_size, void* d_ws, size_t ws_size,
                              hipStream_t stream)
{
    const float* x   = (const float*)d_in[0];
    const float* ew  = (const float*)d_in[1];
    const float* Wp  = (const float*)d_in[2];
    const float* Wl  = (const float*)d_in[3];
    const float* bl  = (const float*)d_in[4];
    const float* Wr  = (const float*)d_in[5];
    const float* br  = (const float*)d_in[6];
    const float* att = (const float*)d_in[7];
    const float* We  = (const float*)d_in[8];
    const float* gb  = (const float*)d_in[9];
    const float* W1  = (const float*)d_in[10];
    const float* b1  = (const float*)d_in[11];
    const float* W2  = (const float*)d_in[12];
    const float* b2  = (const float*)d_in[13];
    const int*   ei  = (const int*)d_in[14];

    int n = in_sizes[0] / IN;
    int E = in_sizes[1];
    const int* src = ei;
    const int* dst = ei + E;

    float* h0    = (float*)d_ws;
    float* xl    = h0 + (size_t)n * HID;
    float* xr    = xl + (size_t)n * HID;
    int*   cnt   = (int*)(xr + (size_t)n * HID);   // zeroed
    int*   off   = cnt + n;
    int*   bsum  = off + n;
    int*   boff  = bsum + 1024;
    int*   rank  = boff + 1024;
    int2*  csr   = (int2*)(rank + ((E + 1) & ~1));

    float* hout   = (float*)d_out;
    float* logits = hout + (size_t)n * HID;

    hipMemsetAsync(cnt, 0, (size_t)n * sizeof(int), stream);

    int rb = (n + 63) / 64;
    int nb = (n + 1023) / 1024;
    int Eb = (E + 255) / 256;

    k_pre_hist<<<rb + Eb, 256, 0, stream>>>(x, Wp, h0, n, dst, cnt, rank, E, rb);
    k_lr_scan1<<<rb + nb, 256, 0, stream>>>(h0, Wl, bl, Wr, br, xl, xr, n, cnt, off, bsum, rb);
    k_scan2<<<1, 1024, 0, stream>>>(bsum, boff, nb);
    k_scan3<<<(n + 255) / 256, 256, 0, stream>>>(off, boff, n);
    k_scatter<<<(E / 4 + 255) / 256, 256, 0, stream>>>(src, dst, ew, off, rank, csr, E);
    k_agg <<<(n + 3) / 4, 256, 0, stream>>>(off, csr, xl, xr, h0, We, att, gb, hout, n, E);
    k_mlp <<<rb, 256, 0, stream>>>(hout, W1, b1, W2, b2, logits, n);
}